// Round 9
// baseline (1591.738 us; speedup 1.0000x reference)
//
#include <hip/hip_runtime.h>
#include <math.h>

#define BATCH 16
#define NPTS  1024
#define KNN   20
#define BNEPS 1e-5f

typedef __attribute__((ext_vector_type(8))) short bf16x8;
typedef __attribute__((ext_vector_type(4))) float f32x4;
typedef __attribute__((ext_vector_type(4))) unsigned short u16x4;

__device__ __forceinline__ float bf2f(unsigned short h) {
  return __uint_as_float(((unsigned int)h) << 16);
}
__device__ __forceinline__ unsigned short f2bf(float f) {
  unsigned int u = __float_as_uint(f);
  u += 0x7fffu + ((u >> 16) & 1u);
  return (unsigned short)(u >> 16);
}

// ================================================================ head mega-kernel
// roles: [0,1024) knn3+topk ; [1024,1536) K=3 GEMM (inline W2) ; [1536,3760) weight prep
__global__ __launch_bounds__(256) void mega_head(
    const float* __restrict__ x, const float* __restrict__ w1, const float* __restrict__ w2,
    const float* __restrict__ w3, const float* __restrict__ w4, const float* __restrict__ w5,
    unsigned short* __restrict__ W2H2, unsigned short* __restrict__ W2L2,
    unsigned short* __restrict__ W2H3, unsigned short* __restrict__ W2L3,
    unsigned short* __restrict__ W2H4, unsigned short* __restrict__ W2L4,
    unsigned short* __restrict__ w5H, unsigned short* __restrict__ w5L,
    int* __restrict__ idx, float* __restrict__ Ab, float* __restrict__ Bb) {
  __shared__ float smem[4096];
  int blk = blockIdx.x;
  int tid = threadIdx.x;

  if (blk < 1024) {
    // ---------------- knn3 + radix top-20 (reads x directly; values identical to old xt path)
    float* cx = smem;
    float* cy = smem + 1024;
    float* cz = smem + 2048;
    float* cn = smem + 3072;
    int lane = tid & 63, w = tid >> 6;
    int pt0 = blk * 16;
    int b = pt0 >> 10;
    for (int p = tid; p < NPTS; p += 256) {
      float xv = x[(size_t)(b * 3 + 0) * NPTS + p];
      float yv = x[(size_t)(b * 3 + 1) * NPTS + p];
      float zv = x[(size_t)(b * 3 + 2) * NPTS + p];
      cx[p] = xv; cy[p] = yv; cz[p] = zv;
      float s = 0.f;
      s = fmaf(xv, xv, s); s = fmaf(yv, yv, s); s = fmaf(zv, zv, s);
      cn[p] = s;
    }
    __syncthreads();
    for (int rr = 0; rr < 4; rr++) {
      int pt = pt0 + w * 4 + rr;
      int lr = pt & 1023;
      float rx = cx[lr], ry = cy[lr], rz = cz[lr], rn = cn[lr];
      unsigned key[16];
#pragma unroll
      for (int s = 0; s < 16; s++) {
        int col = lane + s * 64;
        float acc = 0.f;
        acc = fmaf(rx, cx[col], acc);
        acc = fmaf(ry, cy[col], acc);
        acc = fmaf(rz, cz[col], acc);
        float pdv = fmaf(2.f, acc, -rn) - cn[col];
        unsigned bb = __float_as_uint(pdv);
        key[s] = bb ^ ((((int)bb >> 31) | 0x80000000u));
      }
      unsigned P = 0;
      for (int bit = 31; bit >= 0; --bit) {
        unsigned T = P | (1u << bit);
        int c = 0;
#pragma unroll
        for (int s = 0; s < 16; s++)
          c += __popcll(__ballot(key[s] >= T));
        if (c >= 20) {
          P = T;
          if (c == 20) break;
        }
      }
      unsigned long long ltmask = (1ull << lane) - 1ull;
      int* o = idx + pt * KNN;
      int base = 0;
#pragma unroll
      for (int s = 0; s < 16; s++) {
        unsigned long long m = __ballot(key[s] > P);
        if (key[s] > P) o[base + __popcll(m & ltmask)] = s * 64 + lane;
        base += __popcll(m);
      }
#pragma unroll
      for (int s = 0; s < 16; s++) {
        unsigned long long m = __ballot(key[s] == P);
        if (key[s] == P) {
          int pos = base + __popcll(m & ltmask);
          if (pos < KNN) o[pos] = s * 64 + lane;
        }
        base += __popcll(m);
      }
    }
    return;
  }
  if (blk < 1536) {
    // ---------------- stage-1 f32 GEMM, K=3, inline W2 from w1
    float* As = smem;            // [16][68]
    float* Ws = smem + 1088;     // [16][68]
    int g = blk - 1024;
    int n0 = (g & 1) * 64;
    int m0 = (g >> 1) * 64;
    int tx = tid & 15, ty = tid >> 4;
    float acc[4][4] = {};
#pragma unroll
    for (int l = 0; l < 4; l++) {
      int e = tid + l * 256;
      int m = e >> 4, k = e & 15;
      float av = 0.f, wv = 0.f;
      if (k < 3) {
        int p = m0 + m;
        int b = p >> 10, n = p & 1023;
        av = x[(size_t)(b * 3 + k) * NPTS + n];
        int o = n0 + m;
        if (o < 64) wv = w1[o * 6 + k];
        else        wv = w1[(o - 64) * 6 + 3 + k] - w1[(o - 64) * 6 + k];
      }
      As[k * 68 + m] = av;
      Ws[k * 68 + m] = wv;
    }
    __syncthreads();
    float a[4], wv2[4];
#pragma unroll
    for (int kk = 0; kk < 3; kk++) {
      float4 ra = *(const float4*)&As[kk * 68 + ty * 4];
      float4 rb = *(const float4*)&Ws[kk * 68 + tx * 4];
      a[0] = ra.x; a[1] = ra.y; a[2] = ra.z; a[3] = ra.w;
      wv2[0] = rb.x; wv2[1] = rb.y; wv2[2] = rb.z; wv2[3] = rb.w;
#pragma unroll
      for (int i2 = 0; i2 < 4; i2++)
#pragma unroll
        for (int j = 0; j < 4; j++)
          acc[i2][j] = fmaf(a[i2], wv2[j], acc[i2][j]);
    }
#pragma unroll
    for (int i2 = 0; i2 < 4; i2++) {
      int row = m0 + ty * 4 + i2;
#pragma unroll
      for (int j = 0; j < 4; j++) {
        int col = n0 + tx * 4 + j;
        if (col < 64) Ab[(size_t)row * 64 + col] = acc[i2][j];
        else          Bb[(size_t)row * 64 + (col - 64)] = acc[i2][j];
      }
    }
    return;
  }
  // ---------------- weight prep
  int p = blk - 1536;
  if (p < 2048) {
    int i = p * 256 + tid;
    float v = w5[i];
    unsigned short h = f2bf(v);
    w5H[i] = h;
    w5L[i] = f2bf(v - bf2f(h));
    return;
  }
  p -= 2048;
  const float* w;
  unsigned short *H, *L;
  int C, O;
  if (p < 16)      { w = w2; H = W2H2; L = W2L2; C = 64;  O = 64; }
  else if (p < 48) { w = w3; H = W2H3; L = W2L3; C = 64;  O = 128; p -= 16; }
  else             { w = w4; H = W2H4; L = W2L4; C = 128; O = 256; p -= 48; }
  int i = p * 256 + tid;
  int o = i / C, c = i - o * C;
  float wl = w[o * 2 * C + c];
  float d  = w[o * 2 * C + C + c] - wl;
  unsigned short h1 = f2bf(wl);
  H[(size_t)o * C + c] = h1;
  L[(size_t)o * C + c] = f2bf(wl - bf2f(h1));
  unsigned short h2 = f2bf(d);
  H[(size_t)(O + o) * C + c] = h2;
  L[(size_t)(O + o) * C + c] = f2bf(d - bf2f(h2));
}

// ---------------------------------------------------------------- Gram via bf16x3 MFMA, symmetric (upper triangle)
__global__ __launch_bounds__(256) void gram_mfma(
    const unsigned short* __restrict__ H, const unsigned short* __restrict__ L,
    int ld, int C, const float* __restrict__ xx, float* __restrict__ pd) {
  __shared__ unsigned short lds[4][128 * 32];
  int tid = threadIdx.x;
  int lane = tid & 63, w = tid >> 6;
  int d = blockIdx.x;
  int nd = (d & 7) * (gridDim.x >> 3) + (d >> 3);
  int b = nd / 36;
  int t = nd - b * 36;
  int ti = 0;
  while (t >= 8 - ti) { t -= 8 - ti; ti++; }
  int m0 = ti * 128, n0 = (ti + t) * 128;
  int base = b * NPTS;
  int wrow = (w >> 1) * 64, wcol = (w & 1) * 64;

  f32x4 acc[4][4];
#pragma unroll
  for (int m = 0; m < 4; m++)
#pragma unroll
    for (int n = 0; n < 4; n++) acc[m][n] = (f32x4){0.f, 0.f, 0.f, 0.f};

  const unsigned short* gsrc = (w == 0 || w == 2) ? H : L;
  int b0 = (w < 2) ? m0 : n0;
  int srow = lane >> 2;
  int physChunk = lane & 3;
  int fr = lane & 15, ko = lane >> 4;
  int lsw = (srow & 3) ^ ((srow >> 2) & 3);
  int lchunk = physChunk ^ lsw;
  int koX = ko ^ ((fr & 3) ^ ((fr >> 2) & 3));

  for (int kt = 0; kt < C; kt += 32) {
#pragma unroll
    for (int i = 0; i < 8; i++) {
      int row = i * 16 + srow;
      const unsigned short* g = gsrc + (size_t)(base + b0 + row) * ld + kt + lchunk * 8;
      unsigned short* l = &lds[w][i * 512];
      __builtin_amdgcn_global_load_lds(
          (const __attribute__((address_space(1))) unsigned int*)g,
          (__attribute__((address_space(3))) unsigned int*)l, 16, 0, 0);
    }
    __syncthreads();

    bf16x8 ah[4], al[4], bh[4], bl[4];
#pragma unroll
    for (int m = 0; m < 4; m++) {
      int row = wrow + m * 16 + fr;
      int off = row * 64 + koX * 16;
      ah[m] = *(const bf16x8*)((const char*)&lds[0][0] + off);
      al[m] = *(const bf16x8*)((const char*)&lds[1][0] + off);
    }
#pragma unroll
    for (int n = 0; n < 4; n++) {
      int row = wcol + n * 16 + fr;
      int off = row * 64 + koX * 16;
      bh[n] = *(const bf16x8*)((const char*)&lds[2][0] + off);
      bl[n] = *(const bf16x8*)((const char*)&lds[3][0] + off);
    }
#pragma unroll
    for (int m = 0; m < 4; m++)
#pragma unroll
      for (int n = 0; n < 4; n++) {
        acc[m][n] = __builtin_amdgcn_mfma_f32_16x16x32_bf16(ah[m], bh[n], acc[m][n], 0, 0, 0);
        acc[m][n] = __builtin_amdgcn_mfma_f32_16x16x32_bf16(al[m], bh[n], acc[m][n], 0, 0, 0);
        acc[m][n] = __builtin_amdgcn_mfma_f32_16x16x32_bf16(ah[m], bl[n], acc[m][n], 0, 0, 0);
      }
    __syncthreads();
  }

  int fq = lane >> 4;
#pragma unroll
  for (int n = 0; n < 4; n++) {
    int gc = n0 + wcol + n * 16 + fr;
    float xn = xx[base + gc];
#pragma unroll
    for (int m = 0; m < 4; m++) {
      f32x4 v;
#pragma unroll
      for (int r = 0; r < 4; r++) {
        int gr = m0 + wrow + m * 16 + fq * 4 + r;
        v[r] = fmaf(2.f, acc[m][n][r], -xx[base + gr]) - xn;
        pd[((size_t)(base + gr)) * NPTS + gc] = v[r];
      }
      if (m0 != n0) {
        int gr0 = m0 + wrow + m * 16 + fq * 4;
        *(f32x4*)&pd[((size_t)(base + gc)) * NPTS + gr0] = v;
      }
    }
  }
}

// ================================================================ combined stage GEMM + topk
// blocks [0,ngemm): bf16x3 MFMA GEMM (EPI=1 split write); blocks [ngemm, +4096): radix top-20.
template<int BM>
__global__ __launch_bounds__(256) void gemm_topk(
    const unsigned short* __restrict__ AH, const unsigned short* __restrict__ AL, int lda,
    const unsigned short* __restrict__ BH, const unsigned short* __restrict__ BL, int ldb,
    int K, int N, int ngemm, int gx,
    float* __restrict__ out0, float* __restrict__ out1,
    const float* __restrict__ pd, int* __restrict__ idx) {
  constexpr int MR = BM / 32;
  __shared__ unsigned short lds[4][128 * 32];
  int tid = threadIdx.x;
  int lane = tid & 63, w = tid >> 6;

  if ((int)blockIdx.x >= ngemm) {
    // ---------------- topk role
    int td = blockIdx.x - ngemm;
    int nd = (td & 7) * (4096 >> 3) + (td >> 3);
    int row = nd * 4 + w;
    const float* p = pd + (size_t)row * NPTS;
    unsigned key[16];
#pragma unroll
    for (int s = 0; s < 16; s++) {
      unsigned b = __float_as_uint(p[lane + s * 64]);
      key[s] = b ^ ((((int)b >> 31) | 0x80000000u));
    }
    unsigned P = 0;
    for (int bit = 31; bit >= 0; --bit) {
      unsigned T = P | (1u << bit);
      int c = 0;
#pragma unroll
      for (int s = 0; s < 16; s++)
        c += __popcll(__ballot(key[s] >= T));
      if (c >= 20) {
        P = T;
        if (c == 20) break;
      }
    }
    unsigned long long ltmask = (1ull << lane) - 1ull;
    int* o = idx + row * KNN;
    int base = 0;
#pragma unroll
    for (int s = 0; s < 16; s++) {
      unsigned long long m = __ballot(key[s] > P);
      if (key[s] > P) o[base + __popcll(m & ltmask)] = s * 64 + lane;
      base += __popcll(m);
    }
#pragma unroll
    for (int s = 0; s < 16; s++) {
      unsigned long long m = __ballot(key[s] == P);
      if (key[s] == P) {
        int pos = base + __popcll(m & ltmask);
        if (pos < KNN) o[pos] = s * 64 + lane;
      }
      base += __popcll(m);
    }
    return;
  }

  // ---------------- GEMM role
  int d = blockIdx.x;
  int nd = (d & 7) * (ngemm >> 3) + (d >> 3);
  int n0 = (nd % gx) * 128;
  int m0 = (nd / gx) * BM;
  int wrow = (w >> 1) * (BM / 2), wcol = (w & 1) * 64;

  f32x4 acc[MR][4];
#pragma unroll
  for (int m = 0; m < MR; m++)
#pragma unroll
    for (int n = 0; n < 4; n++) acc[m][n] = (f32x4){0.f, 0.f, 0.f, 0.f};

  const unsigned short* gsrc = (w == 0) ? AH : (w == 1) ? AL : (w == 2) ? BH : BL;
  int ld = (w < 2) ? lda : ldb;
  int b0 = (w < 2) ? m0 : n0;
  int nrow16 = (w < 2) ? (BM / 16) : 8;
  int srow = lane >> 2;
  int physChunk = lane & 3;
  int fr = lane & 15, ko = lane >> 4;
  int lsw = (srow & 3) ^ ((srow >> 2) & 3);
  int lchunk = physChunk ^ lsw;
  int koX = ko ^ ((fr & 3) ^ ((fr >> 2) & 3));

  for (int kt = 0; kt < K; kt += 32) {
    for (int i = 0; i < nrow16; i++) {
      int row = i * 16 + srow;
      const unsigned short* g = gsrc + (size_t)(b0 + row) * ld + kt + lchunk * 8;
      unsigned short* l = &lds[w][i * 512];
      __builtin_amdgcn_global_load_lds(
          (const __attribute__((address_space(1))) unsigned int*)g,
          (__attribute__((address_space(3))) unsigned int*)l, 16, 0, 0);
    }
    __syncthreads();

    bf16x8 ah[MR], al[MR], bh[4], bl[4];
#pragma unroll
    for (int m = 0; m < MR; m++) {
      int row = wrow + m * 16 + fr;
      int off = row * 64 + koX * 16;
      ah[m] = *(const bf16x8*)((const char*)&lds[0][0] + off);
      al[m] = *(const bf16x8*)((const char*)&lds[1][0] + off);
    }
#pragma unroll
    for (int n = 0; n < 4; n++) {
      int row = wcol + n * 16 + fr;
      int off = row * 64 + koX * 16;
      bh[n] = *(const bf16x8*)((const char*)&lds[2][0] + off);
      bl[n] = *(const bf16x8*)((const char*)&lds[3][0] + off);
    }
#pragma unroll
    for (int m = 0; m < MR; m++)
#pragma unroll
      for (int n = 0; n < 4; n++) {
        acc[m][n] = __builtin_amdgcn_mfma_f32_16x16x32_bf16(ah[m], bh[n], acc[m][n], 0, 0, 0);
        acc[m][n] = __builtin_amdgcn_mfma_f32_16x16x32_bf16(al[m], bh[n], acc[m][n], 0, 0, 0);
        acc[m][n] = __builtin_amdgcn_mfma_f32_16x16x32_bf16(ah[m], bl[n], acc[m][n], 0, 0, 0);
      }
    __syncthreads();
  }

  int fq = lane >> 4;
#pragma unroll
  for (int n = 0; n < 4; n++) {
    int gc = n0 + wcol + n * 16 + fr;
    int O = N >> 1;
    float* dst = (gc < O) ? out0 : out1;
    int cc = (gc < O) ? gc : gc - O;
#pragma unroll
    for (int m = 0; m < MR; m++)
#pragma unroll
      for (int r = 0; r < 4; r++) {
        int gr = m0 + wrow + m * 16 + fq * 4 + r;
        dst[(size_t)gr * O + cc] = acc[m][n][r];
      }
  }
}

// ---------------------------------------------------------------- w5 GEMM + BN + LReLU + fused pool (unchanged)
__global__ __launch_bounds__(256) void mfma_gemm_pool(
    const unsigned short* __restrict__ AH, const unsigned short* __restrict__ AL, int lda,
    const unsigned short* __restrict__ BH, const unsigned short* __restrict__ BL, int ldb,
    int K, int N, const float* __restrict__ bnp,
    float* __restrict__ out0, float* __restrict__ out1) {
  __shared__ unsigned short lds[4][128 * 32];
  __shared__ float pm[128];
  __shared__ float ps[128];
  int tid = threadIdx.x;
  int lane = tid & 63, w = tid >> 6;
  int total = gridDim.x * gridDim.y;
  int d = blockIdx.x + gridDim.x * blockIdx.y;
  int nd = (d & 7) * (total >> 3) + (d >> 3);
  int n0 = (nd % gridDim.x) * 128;
  int m0 = (nd / gridDim.x) * 128;
  int wrow = (w >> 1) * 64, wcol = (w & 1) * 64;

  f32x4 acc[4][4];
#pragma unroll
  for (int m = 0; m < 4; m++)
#pragma unroll
    for (int n = 0; n < 4; n++) acc[m][n] = (f32x4){0.f, 0.f, 0.f, 0.f};

  const unsigned short* gsrc = (w == 0) ? AH : (w == 1) ? AL : (w == 2) ? BH : BL;
  int ld = (w < 2) ? lda : ldb;
  int b0 = (w < 2) ? m0 : n0;
  int srow = lane >> 2;
  int physChunk = lane & 3;
  int fr = lane & 15, ko = lane >> 4;
  int lsw = (srow & 3) ^ ((srow >> 2) & 3);
  int lchunk = physChunk ^ lsw;
  int koX = ko ^ ((fr & 3) ^ ((fr >> 2) & 3));

  for (int kt = 0; kt < K; kt += 32) {
#pragma unroll
    for (int i = 0; i < 8; i++) {
      int row = i * 16 + srow;
      const unsigned short* g = gsrc + (size_t)(b0 + row) * ld + kt + lchunk * 8;
      unsigned short* l = &lds[w][i * 512];
      __builtin_amdgcn_global_load_lds(
          (const __attribute__((address_space(1))) unsigned int*)g,
          (__attribute__((address_space(3))) unsigned int*)l, 16, 0, 0);
    }
    __syncthreads();

    bf16x8 ah[4], al[4], bh[4], bl[4];
#pragma unroll
    for (int m = 0; m < 4; m++) {
      int row = wrow + m * 16 + fr;
      int off = row * 64 + koX * 16;
      ah[m] = *(const bf16x8*)((const char*)&lds[0][0] + off);
      al[m] = *(const bf16x8*)((const char*)&lds[1][0] + off);
    }
#pragma unroll
    for (int n = 0; n < 4; n++) {
      int row = wcol + n * 16 + fr;
      int off = row * 64 + koX * 16;
      bh[n] = *(const bf16x8*)((const char*)&lds[2][0] + off);
      bl[n] = *(const bf16x8*)((const char*)&lds[3][0] + off);
    }
#pragma unroll
    for (int m = 0; m < 4; m++)
#pragma unroll
      for (int n = 0; n < 4; n++) {
        acc[m][n] = __builtin_amdgcn_mfma_f32_16x16x32_bf16(ah[m], bh[n], acc[m][n], 0, 0, 0);
        acc[m][n] = __builtin_amdgcn_mfma_f32_16x16x32_bf16(al[m], bh[n], acc[m][n], 0, 0, 0);
        acc[m][n] = __builtin_amdgcn_mfma_f32_16x16x32_bf16(ah[m], bl[n], acc[m][n], 0, 0, 0);
      }
    __syncthreads();
  }

  int fq = lane >> 4;
  float cmax[4], csum[4];
#pragma unroll
  for (int n = 0; n < 4; n++) {
    int gc = n0 + wcol + n * 16 + fr;
    float g = bnp[gc], bt = bnp[N + gc], mu = bnp[2 * N + gc], va = bnp[3 * N + gc];
    float sc = g * rsqrtf(va + BNEPS);
    float mx = -INFINITY, sm = 0.f;
#pragma unroll
    for (int m = 0; m < 4; m++)
#pragma unroll
      for (int r = 0; r < 4; r++) {
        float y = sc * (acc[m][n][r] - mu) + bt;
        y = y >= 0.f ? y : 0.2f * y;
        mx = fmaxf(mx, y);
        sm += y;
      }
    mx = fmaxf(mx, __shfl_xor(mx, 16));
    mx = fmaxf(mx, __shfl_xor(mx, 32));
    sm += __shfl_xor(sm, 16);
    sm += __shfl_xor(sm, 32);
    cmax[n] = mx;
    csum[n] = sm;
  }
  if (w >= 2 && fq == 0) {
#pragma unroll
    for (int n = 0; n < 4; n++) {
      pm[wcol + n * 16 + fr] = cmax[n];
      ps[wcol + n * 16 + fr] = csum[n];
    }
  }
  __syncthreads();
  if (w < 2 && fq == 0) {
    int rb = m0 >> 7;
#pragma unroll
    for (int n = 0; n < 4; n++) {
      int cc = wcol + n * 16 + fr;
      int gc = n0 + cc;
      out0[(size_t)rb * 1024 + gc] = fmaxf(cmax[n], pm[cc]);
      out1[(size_t)rb * 1024 + gc] = csum[n] + ps[cc];
    }
  }
}

// ---------------------------------------------------------------- gather + max_k + BN + LReLU -> bf16 hi/lo cat
template<int O, int XXOUT>
__global__ void gather_max_bn(const float* __restrict__ Ab, const float* __restrict__ Bb,
                              const int* __restrict__ idx, const float* __restrict__ bnp,
                              unsigned short* __restrict__ catH, unsigned short* __restrict__ catL,
                              float* __restrict__ xx, int co) {
  constexpr int LPP = O / 4;
  constexpr int PPB = 1024 / O;
  int tid = threadIdx.x;
  int lp = tid / LPP;
  int cl = tid - lp * LPP;
  int nblk = gridDim.x;
  int d = blockIdx.x;
  int nd = (d & 7) * (nblk >> 3) + (d >> 3);
  int pt = nd * PPB + lp;
  int b = pt >> 10;
  const int* ix = idx + pt * KNN;
  const float4* Ab4 = (const float4*)Ab + (size_t)(b << 10) * LPP;

  float4 mx = {-INFINITY, -INFINITY, -INFINITY, -INFINITY};
#pragma unroll
  for (int k = 0; k < KNN; k++) {
    float4 v = Ab4[(size_t)ix[k] * LPP + cl];
    mx.x = fmaxf(mx.x, v.x);
    mx.y = fmaxf(mx.y, v.y);
    mx.z = fmaxf(mx.z, v.z);
    mx.w = fmaxf(mx.w, v.w);
  }
  float4 bb = ((const float4*)Bb)[(size_t)pt * LPP + cl];
  int o = cl * 4;
  float4 gg = *(const float4*)(bnp + o);
  float4 bt = *(const float4*)(bnp + O + o);
  float4 mu = *(const float4*)(bnp + 2 * O + o);
  float4 va = *(const float4*)(bnp + 3 * O + o);

  float h[4] = {mx.x + bb.x, mx.y + bb.y, mx.z + bb.z, mx.w + bb.w};
  float G[4] = {gg.x, gg.y, gg.z, gg.w};
  float B[4] = {bt.x, bt.y, bt.z, bt.w};
  float M[4] = {mu.x, mu.y, mu.z, mu.w};
  float V[4] = {va.x, va.y, va.z, va.w};

  u16x4 hh, ll;
  float xs = 0.f;
#pragma unroll
  for (int e = 0; e < 4; e++) {
    float y = G[e] * (h[e] - M[e]) * rsqrtf(V[e] + BNEPS) + B[e];
    y = y >= 0.f ? y : 0.2f * y;
    unsigned short yh = f2bf(y);
    float fh = bf2f(yh);
    unsigned short yl = f2bf(y - fh);
    hh[e] = yh;
    ll[e] = yl;
    if (XXOUT) {
      float a = fh + bf2f(yl);
      xs = fmaf(a, a, xs);
    }
  }
  size_t dst = (size_t)pt * 512 + co + o;
  *(u16x4*)(catH + dst) = hh;
  *(u16x4*)(catL + dst) = ll;

  if (XXOUT) {
#pragma unroll
    for (int s = 1; s < LPP; s <<= 1) xs += __shfl_xor(xs, s);
    if (cl == 0) xx[pt] = xs;
  }
}

// ================================================================ tail: pool fold + fc1 + fc2 + fc3 (one block per batch)
__global__ __launch_bounds__(256) void tail_fc(
    const float* __restrict__ pmax, const float* __restrict__ psum,
    const float* __restrict__ bn6, const float* __restrict__ bn7,
    const float* __restrict__ l1w, const float* __restrict__ l2w, const float* __restrict__ l2b,
    const float* __restrict__ l3w, const float* __restrict__ l3b, float* __restrict__ out) {
  __shared__ float pooled[2048];
  __shared__ float f1s[512];
  __shared__ float f2s[256];
  int b = blockIdx.x, t = threadIdx.x, lane = t & 63, w = t >> 6;
  for (int c = t; c < 1024; c += 256) {
    float mx = -INFINITY, sm = 0.f;
#pragma unroll
    for (int i = 0; i < 8; i++) {
      int rb = b * 8 + i;
      mx = fmaxf(mx, pmax[(size_t)rb * 1024 + c]);
      sm += psum[(size_t)rb * 1024 + c];
    }
    pooled[c] = mx;
    pooled[1024 + c] = sm * (1.f / 1024.f);
  }
  __syncthreads();
  // fc1: 512 outputs, wave-per-output (identical reduce order to old fc_kernel)
  for (int o = w; o < 512; o += 4) {
    const float* wp = l1w + (size_t)o * 2048;
    float s = 0.f;
    for (int c = lane; c < 2048; c += 64) s = fmaf(pooled[c], wp[c], s);
#pragma unroll
    for (int off = 32; off; off >>= 1) s += __shfl_xor(s, off);
    if (lane == 0) {
      float gm = bn6[o], bt = bn6[512 + o], mu = bn6[1024 + o], va = bn6[1536 + o];
      s = gm * (s - mu) * rsqrtf(va + BNEPS) + bt;
      f1s[o] = s >= 0.f ? s : 0.2f * s;
    }
  }
  __syncthreads();
  for (int o = w; o < 256; o += 4) {
    const float* wp = l2w + (size_t)o * 512;
    float s = 0.f;
    for (int c = lane; c < 512; c += 64) s = fmaf(f1s[c], wp[c], s);
#pragma unroll
    for (int off = 32; off; off >>= 1) s += __shfl_xor(s, off);
    if (lane == 0) {
      s += l2b[o];
      float gm = bn7[o], bt = bn7[256 + o], mu = bn7[512 + o], va = bn7[768 + o];
      s = gm * (s - mu) * rsqrtf(va + BNEPS) + bt;
      f2s[o] = s >= 0.f ? s : 0.2f * s;
    }
  }
  __syncthreads();
  for (int o = w; o < 40; o += 4) {
    const float* wp = l3w + (size_t)o * 256;
    float s = 0.f;
    for (int c = lane; c < 256; c += 64) s = fmaf(f2s[c], wp[c], s);
#pragma unroll
    for (int off = 32; off; off >>= 1) s += __shfl_xor(s, off);
    if (lane == 0) out[b * 40 + o] = s + l3b[o];
  }
}

// ================================================================ launch
extern "C" void kernel_launch(void* const* d_in, const int* in_sizes, int n_in,
                              void* d_out, int out_size, void* d_ws, size_t ws_size,
                              hipStream_t stream) {
  const float* x   = (const float*)d_in[0];
  const float* w1  = (const float*)d_in[1];
  const float* w2  = (const float*)d_in[2];
  const float* w3  = (const float*)d_in[3];
  const float* w4  = (const float*)d_in[4];
  const float* w5  = (const float*)d_in[5];
  const float* bn1 = (const float*)d_in[6];
  const float* bn2 = (const float*)d_in[7];
  const float* bn3 = (const float*)d_in[8];
  const float* bn4 = (const float*)d_in[9];
  const float* bn5 = (const float*)d_in[10];
  const float* bn6 = (const float*)d_in[11];
  const float* bn7 = (const float*)d_in[12];
  const float* l1w = (const float*)d_in[13];
  const float* l2w = (const float*)d_in[14];
  const float* l2b = (const float*)d_in[15];
  const float* l3w = (const float*)d_in[16];
  const float* l3b = (const float*)d_in[17];
  float* out = (float*)d_out;

  float* ws = (float*)d_ws;
  size_t off = 0;
  float* xx  = ws + off; off += (size_t)BATCH * NPTS;
  unsigned short* W2H2 = (unsigned short*)(ws + off); off += 8192 / 2;
  unsigned short* W2L2 = (unsigned short*)(ws + off); off += 8192 / 2;
  unsigned short* W2H3 = (unsigned short*)(ws + off); off += 16384 / 2;
  unsigned short* W2L3 = (unsigned short*)(ws + off); off += 16384 / 2;
  unsigned short* W2H4 = (unsigned short*)(ws + off); off += 65536 / 2;
  unsigned short* W2L4 = (unsigned short*)(ws + off); off += 65536 / 2;
  unsigned short* w5H = (unsigned short*)(ws + off); off += (size_t)1024 * 512 / 2;
  unsigned short* w5L = (unsigned short*)(ws + off); off += (size_t)1024 * 512 / 2;
  float* Ab  = ws + off; off += (size_t)BATCH * NPTS * 256;
  float* Bb  = ws + off; off += (size_t)BATCH * NPTS * 256;
  unsigned short* catH = (unsigned short*)(ws + off); off += (size_t)BATCH * NPTS * 512 / 2;
  unsigned short* catL = (unsigned short*)(ws + off); off += (size_t)BATCH * NPTS * 512 / 2;
  float* pd  = ws + off; off += (size_t)BATCH * NPTS * NPTS;
  float* pmax = ws + off; off += (size_t)128 * 1024;
  float* psum = ws + off; off += (size_t)128 * 1024;
  int* idx = (int*)(ws + off);

  // ---------------- head: prep + knn3(topk) + stage-1 GEMM in one launch
  mega_head<<<3760, 256, 0, stream>>>(x, w1, w2, w3, w4, w5,
                                      W2H2, W2L2, W2H3, W2L3, W2H4, W2L4, w5H, w5L,
                                      idx, Ab, Bb);
  gather_max_bn<64, 1><<<1024, 256, 0, stream>>>(Ab, Bb, idx, bn1, catH, catL, xx, 0);

  // ---------------- stage 2 (C=64 -> O=64)
  gram_mfma<<<576, 256, 0, stream>>>(catH + 0, catL + 0, 512, 64, xx, pd);
  gemm_topk<64><<<256 + 4096, 256, 0, stream>>>(
      catH + 0, catL + 0, 512, W2H2, W2L2, 64, 64, 128, 256, 1, Ab, Bb, pd, idx);
  gather_max_bn<64, 1><<<1024, 256, 0, stream>>>(Ab, Bb, idx, bn2, catH, catL, xx, 64);

  // ---------------- stage 3 (C=64 -> O=128)
  gram_mfma<<<576, 256, 0, stream>>>(catH + 64, catL + 64, 512, 64, xx, pd);
  gemm_topk<64><<<512 + 4096, 256, 0, stream>>>(
      catH + 64, catL + 64, 512, W2H3, W2L3, 64, 64, 256, 512, 2, Ab, Bb, pd, idx);
  gather_max_bn<128, 1><<<2048, 256, 0, stream>>>(Ab, Bb, idx, bn3, catH, catL, xx, 128);

  // ---------------- stage 4 (C=128 -> O=256)
  gram_mfma<<<576, 256, 0, stream>>>(catH + 128, catL + 128, 512, 128, xx, pd);
  gemm_topk<128><<<512 + 4096, 256, 0, stream>>>(
      catH + 128, catL + 128, 512, W2H4, W2L4, 128, 128, 512, 512, 4, Ab, Bb, pd, idx);
  gather_max_bn<256, 0><<<4096, 256, 0, stream>>>(Ab, Bb, idx, bn4, catH, catL, nullptr, 256);

  // ---------------- w5 GEMM + BN5 + LReLU + fused pool
  mfma_gemm_pool<<<dim3(8, (BATCH * NPTS) / 128), 256, 0, stream>>>(
      catH, catL, 512, w5H, w5L, 512, 512, 1024, bn5, pmax, psum);

  // ---------------- tail: pool fold + 3 FC layers
  tail_fc<<<16, 256, 0, stream>>>(pmax, psum, bn6, bn7, l1w, l2w, l2b, l3w, l3b, out);
}

// Round 10
// 315.040 us; speedup vs baseline: 5.0525x; 5.0525x over previous
//
#include <hip/hip_runtime.h>
#include <math.h>

#define BATCH 16
#define NPTS  1024
#define KNN   20
#define BNEPS 1e-5f

typedef __attribute__((ext_vector_type(8))) short bf16x8;
typedef __attribute__((ext_vector_type(4))) float f32x4;
typedef __attribute__((ext_vector_type(4))) unsigned short u16x4;

__device__ __forceinline__ float bf2f(unsigned short h) {
  return __uint_as_float(((unsigned int)h) << 16);
}
__device__ __forceinline__ unsigned short f2bf(float f) {
  unsigned int u = __float_as_uint(f);
  u += 0x7fffu + ((u >> 16) & 1u);
  return (unsigned short)(u >> 16);
}

// ================================================================ head mega-kernel
// roles: [0,1024) knn3+topk ; [1024,1536) K=3 GEMM (inline W2) ; [1536,3760) weight prep
__global__ __launch_bounds__(256) void mega_head(
    const float* __restrict__ x, const float* __restrict__ w1, const float* __restrict__ w2,
    const float* __restrict__ w3, const float* __restrict__ w4, const float* __restrict__ w5,
    unsigned short* __restrict__ W2H2, unsigned short* __restrict__ W2L2,
    unsigned short* __restrict__ W2H3, unsigned short* __restrict__ W2L3,
    unsigned short* __restrict__ W2H4, unsigned short* __restrict__ W2L4,
    unsigned short* __restrict__ w5H, unsigned short* __restrict__ w5L,
    int* __restrict__ idx, float* __restrict__ Ab, float* __restrict__ Bb) {
  __shared__ float smem[4096];
  int blk = blockIdx.x;
  int tid = threadIdx.x;

  if (blk < 1024) {
    // ---------------- knn3 + radix top-20 (reads x directly)
    float* cx = smem;
    float* cy = smem + 1024;
    float* cz = smem + 2048;
    float* cn = smem + 3072;
    int lane = tid & 63, w = tid >> 6;
    int pt0 = blk * 16;
    int b = pt0 >> 10;
    for (int p = tid; p < NPTS; p += 256) {
      float xv = x[(size_t)(b * 3 + 0) * NPTS + p];
      float yv = x[(size_t)(b * 3 + 1) * NPTS + p];
      float zv = x[(size_t)(b * 3 + 2) * NPTS + p];
      cx[p] = xv; cy[p] = yv; cz[p] = zv;
      float s = 0.f;
      s = fmaf(xv, xv, s); s = fmaf(yv, yv, s); s = fmaf(zv, zv, s);
      cn[p] = s;
    }
    __syncthreads();
    for (int rr = 0; rr < 4; rr++) {
      int pt = pt0 + w * 4 + rr;
      int lr = pt & 1023;
      float rx = cx[lr], ry = cy[lr], rz = cz[lr], rn = cn[lr];
      unsigned key[16];
#pragma unroll
      for (int s = 0; s < 16; s++) {
        int col = lane + s * 64;
        float acc = 0.f;
        acc = fmaf(rx, cx[col], acc);
        acc = fmaf(ry, cy[col], acc);
        acc = fmaf(rz, cz[col], acc);
        float pdv = fmaf(2.f, acc, -rn) - cn[col];
        unsigned bb = __float_as_uint(pdv);
        key[s] = bb ^ ((((int)bb >> 31) | 0x80000000u));
      }
      unsigned P = 0;
      for (int bit = 31; bit >= 0; --bit) {
        unsigned T = P | (1u << bit);
        int c = 0;
#pragma unroll
        for (int s = 0; s < 16; s++)
          c += __popcll(__ballot(key[s] >= T));
        if (c >= 20) {
          P = T;
          if (c == 20) break;
        }
      }
      unsigned long long ltmask = (1ull << lane) - 1ull;
      int* o = idx + pt * KNN;
      int base = 0;
#pragma unroll
      for (int s = 0; s < 16; s++) {
        unsigned long long m = __ballot(key[s] > P);
        if (key[s] > P) o[base + __popcll(m & ltmask)] = s * 64 + lane;
        base += __popcll(m);
      }
#pragma unroll
      for (int s = 0; s < 16; s++) {
        unsigned long long m = __ballot(key[s] == P);
        if (key[s] == P) {
          int pos = base + __popcll(m & ltmask);
          if (pos < KNN) o[pos] = s * 64 + lane;
        }
        base += __popcll(m);
      }
    }
    return;
  }
  if (blk < 1536) {
    // ---------------- stage-1 f32 GEMM, K=3, inline W2 from w1
    float* As = smem;            // [16][68]
    float* Ws = smem + 1088;     // [16][68]
    int g = blk - 1024;
    int n0 = (g & 1) * 64;
    int m0 = (g >> 1) * 64;
    int tx = tid & 15, ty = tid >> 4;
    float acc[4][4] = {};
#pragma unroll
    for (int l = 0; l < 4; l++) {
      int e = tid + l * 256;
      int m = e >> 4, k = e & 15;
      float av = 0.f, wv = 0.f;
      if (k < 3) {
        int p = m0 + m;
        int b = p >> 10, n = p & 1023;
        av = x[(size_t)(b * 3 + k) * NPTS + n];
        int o = n0 + m;
        if (o < 64) wv = w1[o * 6 + k];
        else        wv = w1[(o - 64) * 6 + 3 + k] - w1[(o - 64) * 6 + k];
      }
      As[k * 68 + m] = av;
      Ws[k * 68 + m] = wv;
    }
    __syncthreads();
    float a[4], wv2[4];
#pragma unroll
    for (int kk = 0; kk < 3; kk++) {
      float4 ra = *(const float4*)&As[kk * 68 + ty * 4];
      float4 rb = *(const float4*)&Ws[kk * 68 + tx * 4];
      a[0] = ra.x; a[1] = ra.y; a[2] = ra.z; a[3] = ra.w;
      wv2[0] = rb.x; wv2[1] = rb.y; wv2[2] = rb.z; wv2[3] = rb.w;
#pragma unroll
      for (int i2 = 0; i2 < 4; i2++)
#pragma unroll
        for (int j = 0; j < 4; j++)
          acc[i2][j] = fmaf(a[i2], wv2[j], acc[i2][j]);
    }
#pragma unroll
    for (int i2 = 0; i2 < 4; i2++) {
      int row = m0 + ty * 4 + i2;
#pragma unroll
      for (int j = 0; j < 4; j++) {
        int col = n0 + tx * 4 + j;
        if (col < 64) Ab[(size_t)row * 64 + col] = acc[i2][j];
        else          Bb[(size_t)row * 64 + (col - 64)] = acc[i2][j];
      }
    }
    return;
  }
  // ---------------- weight prep
  int p = blk - 1536;
  if (p < 2048) {
    int i = p * 256 + tid;
    float v = w5[i];
    unsigned short h = f2bf(v);
    w5H[i] = h;
    w5L[i] = f2bf(v - bf2f(h));
    return;
  }
  p -= 2048;
  const float* w;
  unsigned short *H, *L;
  int C, O;
  if (p < 16)      { w = w2; H = W2H2; L = W2L2; C = 64;  O = 64; }
  else if (p < 48) { w = w3; H = W2H3; L = W2L3; C = 64;  O = 128; p -= 16; }
  else             { w = w4; H = W2H4; L = W2L4; C = 128; O = 256; p -= 48; }
  int i = p * 256 + tid;
  int o = i / C, c = i - o * C;
  float wl = w[o * 2 * C + c];
  float d  = w[o * 2 * C + C + c] - wl;
  unsigned short h1 = f2bf(wl);
  H[(size_t)o * C + c] = h1;
  L[(size_t)o * C + c] = f2bf(wl - bf2f(h1));
  unsigned short h2 = f2bf(d);
  H[(size_t)(O + o) * C + c] = h2;
  L[(size_t)(O + o) * C + c] = f2bf(d - bf2f(h2));
}

// ---------------------------------------------------------------- Gram via bf16x3 MFMA, symmetric (upper triangle)
__global__ __launch_bounds__(256) void gram_mfma(
    const unsigned short* __restrict__ H, const unsigned short* __restrict__ L,
    int ld, int C, const float* __restrict__ xx, float* __restrict__ pd) {
  __shared__ unsigned short lds[4][128 * 32];
  int tid = threadIdx.x;
  int lane = tid & 63, w = tid >> 6;
  int d = blockIdx.x;
  int nd = (d & 7) * (gridDim.x >> 3) + (d >> 3);
  int b = nd / 36;
  int t = nd - b * 36;
  int ti = 0;
  while (t >= 8 - ti) { t -= 8 - ti; ti++; }
  int m0 = ti * 128, n0 = (ti + t) * 128;
  int base = b * NPTS;
  int wrow = (w >> 1) * 64, wcol = (w & 1) * 64;

  f32x4 acc[4][4];
#pragma unroll
  for (int m = 0; m < 4; m++)
#pragma unroll
    for (int n = 0; n < 4; n++) acc[m][n] = (f32x4){0.f, 0.f, 0.f, 0.f};

  const unsigned short* gsrc = (w == 0 || w == 2) ? H : L;
  int b0 = (w < 2) ? m0 : n0;
  int srow = lane >> 2;
  int physChunk = lane & 3;
  int fr = lane & 15, ko = lane >> 4;
  int lsw = (srow & 3) ^ ((srow >> 2) & 3);
  int lchunk = physChunk ^ lsw;
  int koX = ko ^ ((fr & 3) ^ ((fr >> 2) & 3));

  for (int kt = 0; kt < C; kt += 32) {
#pragma unroll
    for (int i = 0; i < 8; i++) {
      int row = i * 16 + srow;
      const unsigned short* g = gsrc + (size_t)(base + b0 + row) * ld + kt + lchunk * 8;
      unsigned short* l = &lds[w][i * 512];
      __builtin_amdgcn_global_load_lds(
          (const __attribute__((address_space(1))) unsigned int*)g,
          (__attribute__((address_space(3))) unsigned int*)l, 16, 0, 0);
    }
    __syncthreads();

    bf16x8 ah[4], al[4], bh[4], bl[4];
#pragma unroll
    for (int m = 0; m < 4; m++) {
      int row = wrow + m * 16 + fr;
      int off = row * 64 + koX * 16;
      ah[m] = *(const bf16x8*)((const char*)&lds[0][0] + off);
      al[m] = *(const bf16x8*)((const char*)&lds[1][0] + off);
    }
#pragma unroll
    for (int n = 0; n < 4; n++) {
      int row = wcol + n * 16 + fr;
      int off = row * 64 + koX * 16;
      bh[n] = *(const bf16x8*)((const char*)&lds[2][0] + off);
      bl[n] = *(const bf16x8*)((const char*)&lds[3][0] + off);
    }
#pragma unroll
    for (int m = 0; m < 4; m++)
#pragma unroll
      for (int n = 0; n < 4; n++) {
        acc[m][n] = __builtin_amdgcn_mfma_f32_16x16x32_bf16(ah[m], bh[n], acc[m][n], 0, 0, 0);
        acc[m][n] = __builtin_amdgcn_mfma_f32_16x16x32_bf16(al[m], bh[n], acc[m][n], 0, 0, 0);
        acc[m][n] = __builtin_amdgcn_mfma_f32_16x16x32_bf16(ah[m], bl[n], acc[m][n], 0, 0, 0);
      }
    __syncthreads();
  }

  int fq = lane >> 4;
#pragma unroll
  for (int n = 0; n < 4; n++) {
    int gc = n0 + wcol + n * 16 + fr;
    float xn = xx[base + gc];
#pragma unroll
    for (int m = 0; m < 4; m++) {
      f32x4 v;
#pragma unroll
      for (int r = 0; r < 4; r++) {
        int gr = m0 + wrow + m * 16 + fq * 4 + r;
        v[r] = fmaf(2.f, acc[m][n][r], -xx[base + gr]) - xn;
        pd[((size_t)(base + gr)) * NPTS + gc] = v[r];
      }
      if (m0 != n0) {
        int gr0 = m0 + wrow + m * 16 + fq * 4;
        *(f32x4*)&pd[((size_t)(base + gc)) * NPTS + gr0] = v;
      }
    }
  }
}

// ================================================================ combined stage GEMM + topk
template<int BM>
__global__ __launch_bounds__(256) void gemm_topk(
    const unsigned short* __restrict__ AH, const unsigned short* __restrict__ AL, int lda,
    const unsigned short* __restrict__ BH, const unsigned short* __restrict__ BL, int ldb,
    int K, int N, int ngemm, int gx,
    float* __restrict__ out0, float* __restrict__ out1,
    const float* __restrict__ pd, int* __restrict__ idx) {
  constexpr int MR = BM / 32;
  __shared__ unsigned short lds[4][128 * 32];
  int tid = threadIdx.x;
  int lane = tid & 63, w = tid >> 6;

  if ((int)blockIdx.x >= ngemm) {
    // ---------------- topk role
    int td = blockIdx.x - ngemm;
    int nd = (td & 7) * (4096 >> 3) + (td >> 3);
    int row = nd * 4 + w;
    const float* p = pd + (size_t)row * NPTS;
    unsigned key[16];
#pragma unroll
    for (int s = 0; s < 16; s++) {
      unsigned b = __float_as_uint(p[lane + s * 64]);
      key[s] = b ^ ((((int)b >> 31) | 0x80000000u));
    }
    unsigned P = 0;
    for (int bit = 31; bit >= 0; --bit) {
      unsigned T = P | (1u << bit);
      int c = 0;
#pragma unroll
      for (int s = 0; s < 16; s++)
        c += __popcll(__ballot(key[s] >= T));
      if (c >= 20) {
        P = T;
        if (c == 20) break;
      }
    }
    unsigned long long ltmask = (1ull << lane) - 1ull;
    int* o = idx + row * KNN;
    int base = 0;
#pragma unroll
    for (int s = 0; s < 16; s++) {
      unsigned long long m = __ballot(key[s] > P);
      if (key[s] > P) o[base + __popcll(m & ltmask)] = s * 64 + lane;
      base += __popcll(m);
    }
#pragma unroll
    for (int s = 0; s < 16; s++) {
      unsigned long long m = __ballot(key[s] == P);
      if (key[s] == P) {
        int pos = base + __popcll(m & ltmask);
        if (pos < KNN) o[pos] = s * 64 + lane;
      }
      base += __popcll(m);
    }
    return;
  }

  // ---------------- GEMM role
  int d = blockIdx.x;
  int nd = (d & 7) * (ngemm >> 3) + (d >> 3);
  int n0 = (nd % gx) * 128;
  int m0 = (nd / gx) * BM;
  int wrow = (w >> 1) * (BM / 2), wcol = (w & 1) * 64;

  f32x4 acc[MR][4];
#pragma unroll
  for (int m = 0; m < MR; m++)
#pragma unroll
    for (int n = 0; n < 4; n++) acc[m][n] = (f32x4){0.f, 0.f, 0.f, 0.f};

  const unsigned short* gsrc = (w == 0) ? AH : (w == 1) ? AL : (w == 2) ? BH : BL;
  int ld = (w < 2) ? lda : ldb;
  int b0 = (w < 2) ? m0 : n0;
  int nrow16 = (w < 2) ? (BM / 16) : 8;
  int srow = lane >> 2;
  int physChunk = lane & 3;
  int fr = lane & 15, ko = lane >> 4;
  int lsw = (srow & 3) ^ ((srow >> 2) & 3);
  int lchunk = physChunk ^ lsw;
  int koX = ko ^ ((fr & 3) ^ ((fr >> 2) & 3));

  for (int kt = 0; kt < K; kt += 32) {
    for (int i = 0; i < nrow16; i++) {
      int row = i * 16 + srow;
      const unsigned short* g = gsrc + (size_t)(b0 + row) * ld + kt + lchunk * 8;
      unsigned short* l = &lds[w][i * 512];
      __builtin_amdgcn_global_load_lds(
          (const __attribute__((address_space(1))) unsigned int*)g,
          (__attribute__((address_space(3))) unsigned int*)l, 16, 0, 0);
    }
    __syncthreads();

    bf16x8 ah[MR], al[MR], bh[4], bl[4];
#pragma unroll
    for (int m = 0; m < MR; m++) {
      int row = wrow + m * 16 + fr;
      int off = row * 64 + koX * 16;
      ah[m] = *(const bf16x8*)((const char*)&lds[0][0] + off);
      al[m] = *(const bf16x8*)((const char*)&lds[1][0] + off);
    }
#pragma unroll
    for (int n = 0; n < 4; n++) {
      int row = wcol + n * 16 + fr;
      int off = row * 64 + koX * 16;
      bh[n] = *(const bf16x8*)((const char*)&lds[2][0] + off);
      bl[n] = *(const bf16x8*)((const char*)&lds[3][0] + off);
    }
#pragma unroll
    for (int m = 0; m < MR; m++)
#pragma unroll
      for (int n = 0; n < 4; n++) {
        acc[m][n] = __builtin_amdgcn_mfma_f32_16x16x32_bf16(ah[m], bh[n], acc[m][n], 0, 0, 0);
        acc[m][n] = __builtin_amdgcn_mfma_f32_16x16x32_bf16(al[m], bh[n], acc[m][n], 0, 0, 0);
        acc[m][n] = __builtin_amdgcn_mfma_f32_16x16x32_bf16(ah[m], bl[n], acc[m][n], 0, 0, 0);
      }
    __syncthreads();
  }

  int fq = lane >> 4;
#pragma unroll
  for (int n = 0; n < 4; n++) {
    int gc = n0 + wcol + n * 16 + fr;
    int O = N >> 1;
    float* dst = (gc < O) ? out0 : out1;
    int cc = (gc < O) ? gc : gc - O;
#pragma unroll
    for (int m = 0; m < MR; m++)
#pragma unroll
      for (int r = 0; r < 4; r++) {
        int gr = m0 + wrow + m * 16 + fq * 4 + r;
        dst[(size_t)gr * O + cc] = acc[m][n][r];
      }
  }
}

// ---------------------------------------------------------------- w5 GEMM + BN + LReLU + fused pool
__global__ __launch_bounds__(256) void mfma_gemm_pool(
    const unsigned short* __restrict__ AH, const unsigned short* __restrict__ AL, int lda,
    const unsigned short* __restrict__ BH, const unsigned short* __restrict__ BL, int ldb,
    int K, int N, const float* __restrict__ bnp,
    float* __restrict__ out0, float* __restrict__ out1) {
  __shared__ unsigned short lds[4][128 * 32];
  __shared__ float pm[128];
  __shared__ float ps[128];
  int tid = threadIdx.x;
  int lane = tid & 63, w = tid >> 6;
  int total = gridDim.x * gridDim.y;
  int d = blockIdx.x + gridDim.x * blockIdx.y;
  int nd = (d & 7) * (total >> 3) + (d >> 3);
  int n0 = (nd % gridDim.x) * 128;
  int m0 = (nd / gridDim.x) * 128;
  int wrow = (w >> 1) * 64, wcol = (w & 1) * 64;

  f32x4 acc[4][4];
#pragma unroll
  for (int m = 0; m < 4; m++)
#pragma unroll
    for (int n = 0; n < 4; n++) acc[m][n] = (f32x4){0.f, 0.f, 0.f, 0.f};

  const unsigned short* gsrc = (w == 0) ? AH : (w == 1) ? AL : (w == 2) ? BH : BL;
  int ld = (w < 2) ? lda : ldb;
  int b0 = (w < 2) ? m0 : n0;
  int srow = lane >> 2;
  int physChunk = lane & 3;
  int fr = lane & 15, ko = lane >> 4;
  int lsw = (srow & 3) ^ ((srow >> 2) & 3);
  int lchunk = physChunk ^ lsw;
  int koX = ko ^ ((fr & 3) ^ ((fr >> 2) & 3));

  for (int kt = 0; kt < K; kt += 32) {
#pragma unroll
    for (int i = 0; i < 8; i++) {
      int row = i * 16 + srow;
      const unsigned short* g = gsrc + (size_t)(b0 + row) * ld + kt + lchunk * 8;
      unsigned short* l = &lds[w][i * 512];
      __builtin_amdgcn_global_load_lds(
          (const __attribute__((address_space(1))) unsigned int*)g,
          (__attribute__((address_space(3))) unsigned int*)l, 16, 0, 0);
    }
    __syncthreads();

    bf16x8 ah[4], al[4], bh[4], bl[4];
#pragma unroll
    for (int m = 0; m < 4; m++) {
      int row = wrow + m * 16 + fr;
      int off = row * 64 + koX * 16;
      ah[m] = *(const bf16x8*)((const char*)&lds[0][0] + off);
      al[m] = *(const bf16x8*)((const char*)&lds[1][0] + off);
    }
#pragma unroll
    for (int n = 0; n < 4; n++) {
      int row = wcol + n * 16 + fr;
      int off = row * 64 + koX * 16;
      bh[n] = *(const bf16x8*)((const char*)&lds[2][0] + off);
      bl[n] = *(const bf16x8*)((const char*)&lds[3][0] + off);
    }
#pragma unroll
    for (int m = 0; m < 4; m++)
#pragma unroll
      for (int n = 0; n < 4; n++) {
        acc[m][n] = __builtin_amdgcn_mfma_f32_16x16x32_bf16(ah[m], bh[n], acc[m][n], 0, 0, 0);
        acc[m][n] = __builtin_amdgcn_mfma_f32_16x16x32_bf16(al[m], bh[n], acc[m][n], 0, 0, 0);
        acc[m][n] = __builtin_amdgcn_mfma_f32_16x16x32_bf16(ah[m], bl[n], acc[m][n], 0, 0, 0);
      }
    __syncthreads();
  }

  int fq = lane >> 4;
  float cmax[4], csum[4];
#pragma unroll
  for (int n = 0; n < 4; n++) {
    int gc = n0 + wcol + n * 16 + fr;
    float g = bnp[gc], bt = bnp[N + gc], mu = bnp[2 * N + gc], va = bnp[3 * N + gc];
    float sc = g * rsqrtf(va + BNEPS);
    float mx = -INFINITY, sm = 0.f;
#pragma unroll
    for (int m = 0; m < 4; m++)
#pragma unroll
      for (int r = 0; r < 4; r++) {
        float y = sc * (acc[m][n][r] - mu) + bt;
        y = y >= 0.f ? y : 0.2f * y;
        mx = fmaxf(mx, y);
        sm += y;
      }
    mx = fmaxf(mx, __shfl_xor(mx, 16));
    mx = fmaxf(mx, __shfl_xor(mx, 32));
    sm += __shfl_xor(sm, 16);
    sm += __shfl_xor(sm, 32);
    cmax[n] = mx;
    csum[n] = sm;
  }
  if (w >= 2 && fq == 0) {
#pragma unroll
    for (int n = 0; n < 4; n++) {
      pm[wcol + n * 16 + fr] = cmax[n];
      ps[wcol + n * 16 + fr] = csum[n];
    }
  }
  __syncthreads();
  if (w < 2 && fq == 0) {
    int rb = m0 >> 7;
#pragma unroll
    for (int n = 0; n < 4; n++) {
      int cc = wcol + n * 16 + fr;
      int gc = n0 + cc;
      out0[(size_t)rb * 1024 + gc] = fmaxf(cmax[n], pm[cc]);
      out1[(size_t)rb * 1024 + gc] = csum[n] + ps[cc];
    }
  }
}

// ---------------------------------------------------------------- fold 8 row-block partials per batch
__global__ void reduce_pool(const float* __restrict__ pmax, const float* __restrict__ psum,
                            float* __restrict__ pooled) {
  int c = blockIdx.x * 256 + threadIdx.x;
  int b = blockIdx.y;
  float mx = -INFINITY, sm = 0.f;
#pragma unroll
  for (int i = 0; i < 8; i++) {
    int rb = b * 8 + i;
    mx = fmaxf(mx, pmax[(size_t)rb * 1024 + c]);
    sm += psum[(size_t)rb * 1024 + c];
  }
  pooled[b * 2048 + c] = mx;
  pooled[b * 2048 + 1024 + c] = sm * (1.f / 1024.f);
}

// ---------------------------------------------------------------- gather + max_k + BN + LReLU -> bf16 hi/lo cat
template<int O, int XXOUT>
__global__ void gather_max_bn(const float* __restrict__ Ab, const float* __restrict__ Bb,
                              const int* __restrict__ idx, const float* __restrict__ bnp,
                              unsigned short* __restrict__ catH, unsigned short* __restrict__ catL,
                              float* __restrict__ xx, int co) {
  constexpr int LPP = O / 4;
  constexpr int PPB = 1024 / O;
  int tid = threadIdx.x;
  int lp = tid / LPP;
  int cl = tid - lp * LPP;
  int nblk = gridDim.x;
  int d = blockIdx.x;
  int nd = (d & 7) * (nblk >> 3) + (d >> 3);
  int pt = nd * PPB + lp;
  int b = pt >> 10;
  const int* ix = idx + pt * KNN;
  const float4* Ab4 = (const float4*)Ab + (size_t)(b << 10) * LPP;

  float4 mx = {-INFINITY, -INFINITY, -INFINITY, -INFINITY};
#pragma unroll
  for (int k = 0; k < KNN; k++) {
    float4 v = Ab4[(size_t)ix[k] * LPP + cl];
    mx.x = fmaxf(mx.x, v.x);
    mx.y = fmaxf(mx.y, v.y);
    mx.z = fmaxf(mx.z, v.z);
    mx.w = fmaxf(mx.w, v.w);
  }
  float4 bb = ((const float4*)Bb)[(size_t)pt * LPP + cl];
  int o = cl * 4;
  float4 gg = *(const float4*)(bnp + o);
  float4 bt = *(const float4*)(bnp + O + o);
  float4 mu = *(const float4*)(bnp + 2 * O + o);
  float4 va = *(const float4*)(bnp + 3 * O + o);

  float h[4] = {mx.x + bb.x, mx.y + bb.y, mx.z + bb.z, mx.w + bb.w};
  float G[4] = {gg.x, gg.y, gg.z, gg.w};
  float B[4] = {bt.x, bt.y, bt.z, bt.w};
  float M[4] = {mu.x, mu.y, mu.z, mu.w};
  float V[4] = {va.x, va.y, va.z, va.w};

  u16x4 hh, ll;
  float xs = 0.f;
#pragma unroll
  for (int e = 0; e < 4; e++) {
    float y = G[e] * (h[e] - M[e]) * rsqrtf(V[e] + BNEPS) + B[e];
    y = y >= 0.f ? y : 0.2f * y;
    unsigned short yh = f2bf(y);
    float fh = bf2f(yh);
    unsigned short yl = f2bf(y - fh);
    hh[e] = yh;
    ll[e] = yl;
    if (XXOUT) {
      float a = fh + bf2f(yl);
      xs = fmaf(a, a, xs);
    }
  }
  size_t dst = (size_t)pt * 512 + co + o;
  *(u16x4*)(catH + dst) = hh;
  *(u16x4*)(catL + dst) = ll;

  if (XXOUT) {
#pragma unroll
    for (int s = 1; s < LPP; s <<= 1) xs += __shfl_xor(xs, s);
    if (cl == 0) xx[pt] = xs;
  }
}

// ---------------------------------------------------------------- FC: wave per output
__global__ void fc_kernel(const float* __restrict__ in, const float* __restrict__ w,
                          const float* __restrict__ bias, const float* __restrict__ bnp,
                          float* __restrict__ out, int Cin, int Cout, int act) {
  int g = blockIdx.x * blockDim.x + threadIdx.x;
  int wid = g >> 6, lane = g & 63;
  if (wid >= BATCH * Cout) return;
  int b = wid / Cout, o = wid - b * Cout;
  const float* xp = in + (size_t)b * Cin;
  const float* wp = w + (size_t)o * Cin;
  float s = 0.f;
  for (int c = lane; c < Cin; c += 64) s = fmaf(xp[c], wp[c], s);
#pragma unroll
  for (int off = 32; off; off >>= 1) s += __shfl_xor(s, off);
  if (lane == 0) {
    if (bias) s += bias[o];
    if (act) {
      float gm = bnp[o], bt = bnp[Cout + o], mu = bnp[2 * Cout + o], va = bnp[3 * Cout + o];
      s = gm * (s - mu) * rsqrtf(va + BNEPS) + bt;
      s = s >= 0.f ? s : 0.2f * s;
    }
    out[wid] = s;
  }
}

// ================================================================ launch
extern "C" void kernel_launch(void* const* d_in, const int* in_sizes, int n_in,
                              void* d_out, int out_size, void* d_ws, size_t ws_size,
                              hipStream_t stream) {
  const float* x   = (const float*)d_in[0];
  const float* w1  = (const float*)d_in[1];
  const float* w2  = (const float*)d_in[2];
  const float* w3  = (const float*)d_in[3];
  const float* w4  = (const float*)d_in[4];
  const float* w5  = (const float*)d_in[5];
  const float* bn1 = (const float*)d_in[6];
  const float* bn2 = (const float*)d_in[7];
  const float* bn3 = (const float*)d_in[8];
  const float* bn4 = (const float*)d_in[9];
  const float* bn5 = (const float*)d_in[10];
  const float* bn6 = (const float*)d_in[11];
  const float* bn7 = (const float*)d_in[12];
  const float* l1w = (const float*)d_in[13];
  const float* l2w = (const float*)d_in[14];
  const float* l2b = (const float*)d_in[15];
  const float* l3w = (const float*)d_in[16];
  const float* l3b = (const float*)d_in[17];
  float* out = (float*)d_out;

  float* ws = (float*)d_ws;
  size_t off = 0;
  float* xx  = ws + off; off += (size_t)BATCH * NPTS;
  unsigned short* W2H2 = (unsigned short*)(ws + off); off += 8192 / 2;
  unsigned short* W2L2 = (unsigned short*)(ws + off); off += 8192 / 2;
  unsigned short* W2H3 = (unsigned short*)(ws + off); off += 16384 / 2;
  unsigned short* W2L3 = (unsigned short*)(ws + off); off += 16384 / 2;
  unsigned short* W2H4 = (unsigned short*)(ws + off); off += 65536 / 2;
  unsigned short* W2L4 = (unsigned short*)(ws + off); off += 65536 / 2;
  unsigned short* w5H = (unsigned short*)(ws + off); off += (size_t)1024 * 512 / 2;
  unsigned short* w5L = (unsigned short*)(ws + off); off += (size_t)1024 * 512 / 2;
  float* Ab  = ws + off; off += (size_t)BATCH * NPTS * 256;
  float* Bb  = ws + off; off += (size_t)BATCH * NPTS * 256;
  unsigned short* catH = (unsigned short*)(ws + off); off += (size_t)BATCH * NPTS * 512 / 2;
  unsigned short* catL = (unsigned short*)(ws + off); off += (size_t)BATCH * NPTS * 512 / 2;
  float* pd  = ws + off; off += (size_t)BATCH * NPTS * NPTS;
  float* pmax = ws + off; off += (size_t)128 * 1024;
  float* psum = ws + off; off += (size_t)128 * 1024;
  float* pooled = ws + off; off += (size_t)BATCH * 2048;
  float* f1  = ws + off; off += (size_t)BATCH * 512;
  float* f2  = ws + off; off += (size_t)BATCH * 256;
  int* idx = (int*)(ws + off);

  // ---------------- head: prep + knn3(topk) + stage-1 GEMM in one launch
  mega_head<<<3760, 256, 0, stream>>>(x, w1, w2, w3, w4, w5,
                                      W2H2, W2L2, W2H3, W2L3, W2H4, W2L4, w5H, w5L,
                                      idx, Ab, Bb);
  gather_max_bn<64, 1><<<1024, 256, 0, stream>>>(Ab, Bb, idx, bn1, catH, catL, xx, 0);

  // ---------------- stage 2 (C=64 -> O=64)
  gram_mfma<<<576, 256, 0, stream>>>(catH + 0, catL + 0, 512, 64, xx, pd);
  gemm_topk<64><<<256 + 4096, 256, 0, stream>>>(
      catH + 0, catL + 0, 512, W2H2, W2L2, 64, 64, 128, 256, 1, Ab, Bb, pd, idx);
  gather_max_bn<64, 1><<<1024, 256, 0, stream>>>(Ab, Bb, idx, bn2, catH, catL, xx, 64);

  // ---------------- stage 3 (C=64 -> O=128)
  gram_mfma<<<576, 256, 0, stream>>>(catH + 64, catL + 64, 512, 64, xx, pd);
  gemm_topk<64><<<512 + 4096, 256, 0, stream>>>(
      catH + 64, catL + 64, 512, W2H3, W2L3, 64, 64, 256, 512, 2, Ab, Bb, pd, idx);
  gather_max_bn<128, 1><<<2048, 256, 0, stream>>>(Ab, Bb, idx, bn3, catH, catL, xx, 128);

  // ---------------- stage 4 (C=128 -> O=256)
  gram_mfma<<<576, 256, 0, stream>>>(catH + 128, catL + 128, 512, 128, xx, pd);
  gemm_topk<128><<<512 + 4096, 256, 0, stream>>>(
      catH + 128, catL + 128, 512, W2H4, W2L4, 128, 128, 512, 512, 4, Ab, Bb, pd, idx);
  gather_max_bn<256, 0><<<4096, 256, 0, stream>>>(Ab, Bb, idx, bn4, catH, catL, nullptr, 256);

  // ---------------- w5 GEMM + BN5 + LReLU + fused pool
  mfma_gemm_pool<<<dim3(8, (BATCH * NPTS) / 128), 256, 0, stream>>>(
      catH, catL, 512, w5H, w5L, 512, 512, 1024, bn5, pmax, psum);
  reduce_pool<<<dim3(4, BATCH), 256, 0, stream>>>(pmax, psum, pooled);

  // ---------------- FC tail (wave-per-output, full-GPU parallelism)
  fc_kernel<<<(BATCH * 512 * 64) / 256, 256, 0, stream>>>(pooled, l1w, nullptr, bn6, f1, 2048, 512, 1);
  fc_kernel<<<(BATCH * 256 * 64) / 256, 256, 0, stream>>>(f1, l2w, l2b, bn7, f2, 512, 256, 1);
  fc_kernel<<<(BATCH * 40 * 64 + 255) / 256, 256, 0, stream>>>(f2, l3w, l3b, nullptr, out, 256, 40, 0);
}